// Round 3
// baseline (268.910 us; speedup 1.0000x reference)
//
#include <hip/hip_runtime.h>
#include <math.h>

#define NL 8
#define NP 512
#define NC 64
#define NF 128
#define NALL 192
#define NRAY (NL * NP)
#define HID 128

typedef _Float16 half8 __attribute__((ext_vector_type(8)));
typedef _Float16 half4v __attribute__((ext_vector_type(4)));
typedef float floatx16 __attribute__((ext_vector_type(16)));
typedef unsigned long long ull;

#define MFMA(a, b, c) __builtin_amdgcn_mfma_f32_32x32x16_f16((a), (b), (c), 0, 0, 0)

// r17: on top of r16 (128-pt block, 8 waves, 512 thr):
//  (1) wave remap jq*mh -> jh*mq: B-activation LDS reads deduped 4x -> 2x
//      (LDS was the most-loaded shared pipe ~55%); A weight streams dup 2x->4x
//      but from L2 with immediate offsets (24 TB/s demand < 34.5 ceiling).
//  (2) all swizzled LDS read addresses hoisted to 8 registers computed once
//      (haddr XOR uses only l31&15; addresses identical across both gemms);
//      Hhi/Hlo merged so lo-plane = +32768 DS immediate. A-pointers biased
//      +4KB so all ks immediates fit signed-13-bit global offsets.
//      Removes ~500 VALU/wave of loop addressing.
// Numerics: per-tile 3-MFMA sequence byte-identical to champion; layer-4
// reduce = champion's j-half association -> absmax 0.0 expected.

__device__ __forceinline__ float dcoarse_at(int i) {
    float t = (float)i * 0.015625f; // i/64, exact in fp32
    return 1e-3f * (1.0f - t) + 0.5f * t;
}

__device__ __forceinline__ floatx16 fzero16() {
    floatx16 z;
#pragma unroll
    for (int i = 0; i < 16; ++i) z[i] = 0.f;
    return z;
}
__device__ __forceinline__ half8 hzero8() {
    half8 z;
#pragma unroll
    for (int i = 0; i < 8; ++i) z[i] = (_Float16)0.f;
    return z;
}

// Wsp layout (per layer L in {0:w1, 1:w2}, plane p in {hi,lo}):
//   Wsp[(L*2+p)*16384 + f],  f = (((jb*8+ks)*2+lhi)*32 + l31)*8 + i
//   holding split(w[(ks*16+lhi*8+i)*128 + (jb*32+l31)]).
__global__ void prep_kernel(const float* __restrict__ w1, const float* __restrict__ w2,
                            _Float16* __restrict__ Wsp) {
    int f = blockIdx.x * 256 + threadIdx.x;   // [0, 16384)
    int layer = blockIdx.y;
    const float* w = layer ? w2 : w1;
    int i = f & 7, l31 = (f >> 3) & 31, lhi = (f >> 8) & 1, ks = (f >> 9) & 7, jb = f >> 12;
    int j = jb * 32 + l31;
    int k = ks * 16 + lhi * 8 + i;
    float v = w[k * 128 + j];
    _Float16 hi = (_Float16)v;
    Wsp[(layer * 2 + 0) * 16384 + f] = hi;
    Wsp[(layer * 2 + 1) * 16384 + f] = (_Float16)(v - (float)hi);
}

// Fused 4-layer MLP over 128 points per block, 8 waves, split-fp16 MFMA.
// MODE 0: coarse points (ray = pt>>6). MODE 1: fine points only (ray = pt>>7).
template<int MODE, int FASTW>
__global__ __launch_bounds__(512, 4) void mlp_kernel(
    const float* __restrict__ pts, const float* __restrict__ lights,
    const float* __restrict__ d_fine,
    const float* __restrict__ w0, const float* __restrict__ b0,
    const float* __restrict__ w1, const float* __restrict__ b1,
    const float* __restrict__ w2, const float* __restrict__ b2,
    const float* __restrict__ w3, const float* __restrict__ b3,
    const _Float16* __restrict__ Wsp,
    float* __restrict__ sdf_out)
{
    // H[0] = hi plane, H[1] = lo plane (contiguous: lo = hi + 32768 bytes)
    __shared__ __align__(16) _Float16 H[2 * 128 * 128];
    __shared__ _Float16 Xs[6 * 128];   // hi c0,c1,c2 then lo c0,c1,c2
    __shared__ float P2[2 * 128];      // [jh][m]

    const int tid = threadIdx.x;
    const int lane = tid & 63;
    const int wv = tid >> 6;                 // 0..7
    const int jh = wv & 1, mq = wv >> 1;     // j half (64 cols), m quarter (32 rows)
    const int l31 = lane & 31, lhi = lane >> 5;
    const int base = blockIdx.x * 128;

    // ---- phase A: per-point coords, split to fp16 hi/lo in LDS
    if (tid < 128) {
        int pt = base + tid;
        int ray; float d;
        if (MODE == 0) { ray = pt >> 6; d = dcoarse_at(pt & 63); }
        else           { ray = pt >> 7; d = d_fine[pt]; }
        int l = ray >> 9, p = ray & (NP - 1);
        float px = pts[p * 3 + 0], py = pts[p * 3 + 1], pz = pts[p * 3 + 2];
        float dx = lights[l * 3 + 0] - px, dy = lights[l * 3 + 1] - py, dz = lights[l * 3 + 2] - pz;
        float n = sqrtf(dx * dx + dy * dy + dz * dz);
        dx /= n; dy /= n; dz /= n;
        float xc[3] = { px + d * dx, py + d * dy, pz + d * dz };
#pragma unroll
        for (int c = 0; c < 3; ++c) {
            _Float16 h = (_Float16)xc[c];
            Xs[c * 128 + tid] = h;
            Xs[(3 + c) * 128 + tid] = (_Float16)(xc[c] - (float)h);
        }
    }

    const int m0 = mq * 32;              // this wave's 32-pt quarter
    const int mrow = m0 + l31;           // the LDS row this lane touches
    char* Hb = (char*)H;

    // Hoisted LDS read byte-offsets (identical for both gemms; lo = +32768 imm)
    int rdoff[8];
#pragma unroll
    for (int ks = 0; ks < 8; ++ks) {
        int k0 = ks * 16 + lhi * 8;
        rdoff[ks] = (mrow * 128 + ((((k0 >> 3) ^ (mrow & 15)) << 3) | (k0 & 7))) * 2;
    }

    auto store_tile = [&](const floatx16& a, int jt, const float* __restrict__ bias) {
#pragma unroll
        for (int g = 0; g < 4; ++g) {
            int jg = jh * 64 + jt * 32 + 8 * g + 4 * lhi;
            half4v hq, lq;
#pragma unroll
            for (int q = 0; q < 4; ++q) {
                float v = fmaxf(a[g * 4 + q] + bias[jg + q], 0.f);
                _Float16 hi = (_Float16)v;
                hq[q] = hi;
                lq[q] = (_Float16)(v - (float)hi);
            }
            int ad = (mrow * 128 + ((((jg >> 3) ^ (mrow & 15)) << 3) | (jg & 7))) * 2;
            *(half4v*)(Hb + ad) = hq;
            *(half4v*)(Hb + ad + 32768) = lq;
        }
    };

    floatx16 acc[2];   // [jt] — (jh half: 2x32 j) x 32m per wave

    // A-pointer for (L, plane, jt), biased +2048 halves so ks immediates are
    // ks*1024-4096 in [-4096, 3072] (signed-13-bit global offset).
    const int aoff = lhi * 256 + l31 * 8 + 2048;
    const _Float16* pA00h = Wsp + 0 * 16384 + (jh * 2 + 0) * 4096 + aoff;
    const _Float16* pA00l = Wsp + 1 * 16384 + (jh * 2 + 0) * 4096 + aoff;
    const _Float16* pA01h = Wsp + 0 * 16384 + (jh * 2 + 1) * 4096 + aoff;
    const _Float16* pA01l = Wsp + 1 * 16384 + (jh * 2 + 1) * 4096 + aoff;
    const _Float16* pA10h = Wsp + 2 * 16384 + (jh * 2 + 0) * 4096 + aoff;
    const _Float16* pA10l = Wsp + 3 * 16384 + (jh * 2 + 0) * 4096 + aoff;
    const _Float16* pA11h = Wsp + 2 * 16384 + (jh * 2 + 1) * 4096 + aoff;
    const _Float16* pA11l = Wsp + 3 * 16384 + (jh * 2 + 1) * 4096 + aoff;

    // Slow-path A fetch (fp32 weights, split on the fly) — correctness fallback.
    auto ldA_slow = [&](int L, int jt, int ks, half8& ah, half8& al) {
        const float* w = L ? w2 : w1;
        int j = jh * 64 + jt * 32 + l31, k0 = ks * 16 + lhi * 8;
#pragma unroll
        for (int i = 0; i < 8; ++i) {
            float v = w[(k0 + i) * 128 + j];
            _Float16 hi = (_Float16)v;
            ah[i] = hi;
            al[i] = (_Float16)(v - (float)hi);
        }
    };

    // gemm over K=128: B read once per ks (2 reads), A for both j-tiles (4 loads).
    // pf* = prefetched ks=0 A fragments (loaded before the preceding barrier).
    auto gemm = [&](int L, const _Float16* p0h, const _Float16* p0l,
                    const _Float16* p1h, const _Float16* p1l,
                    half8 pf0h, half8 pf0l, half8 pf1h, half8 pf1l) {
        acc[0] = fzero16(); acc[1] = fzero16();
#pragma unroll
        for (int ks = 0; ks < 8; ++ks) {
            half8 bh = *(const half8*)(Hb + rdoff[ks]);
            half8 bl = *(const half8*)(Hb + rdoff[ks] + 32768);
            half8 a0h, a0l, a1h, a1l;
            if (FASTW) {
                if (ks == 0) { a0h = pf0h; a0l = pf0l; a1h = pf1h; a1l = pf1l; }
                else {
                    a0h = *(const half8*)(p0h + ks * 512 - 2048);
                    a0l = *(const half8*)(p0l + ks * 512 - 2048);
                    a1h = *(const half8*)(p1h + ks * 512 - 2048);
                    a1l = *(const half8*)(p1l + ks * 512 - 2048);
                }
            } else {
                ldA_slow(L, 0, ks, a0h, a0l);
                ldA_slow(L, 1, ks, a1h, a1l);
            }
            acc[0] = MFMA(a0l, bh, acc[0]); acc[1] = MFMA(a1l, bh, acc[1]);
            acc[0] = MFMA(a0h, bl, acc[0]); acc[1] = MFMA(a1h, bl, acc[1]);
            acc[0] = MFMA(a0h, bh, acc[0]); acc[1] = MFMA(a1h, bh, acc[1]);
        }
    };

    __syncthreads();   // Xs visible

    // ---- Layer 1: 3->128 as one K=16 MFMA step (k>=3 zero-padded)
    {
        half8 a1h[2], a1l[2], bh1 = hzero8(), bl1 = hzero8();
        a1h[0] = hzero8(); a1h[1] = hzero8(); a1l[0] = hzero8(); a1l[1] = hzero8();
        if (lhi == 0) {
#pragma unroll
            for (int jt = 0; jt < 2; ++jt) {
                int j = jh * 64 + jt * 32 + l31;
#pragma unroll
                for (int c = 0; c < 3; ++c) {
                    float v = w0[c * 128 + j];
                    _Float16 hi = (_Float16)v;
                    a1h[jt][c] = hi;
                    a1l[jt][c] = (_Float16)(v - (float)hi);
                }
            }
#pragma unroll
            for (int c = 0; c < 3; ++c) {
                bh1[c] = Xs[c * 128 + mrow];
                bl1[c] = Xs[(3 + c) * 128 + mrow];
            }
        }
        acc[0] = fzero16(); acc[1] = fzero16();
        acc[0] = MFMA(a1l[0], bh1, acc[0]); acc[1] = MFMA(a1l[1], bh1, acc[1]);
        acc[0] = MFMA(a1h[0], bl1, acc[0]); acc[1] = MFMA(a1h[1], bl1, acc[1]);
        acc[0] = MFMA(a1h[0], bh1, acc[0]); acc[1] = MFMA(a1h[1], bh1, acc[1]);
        store_tile(acc[0], 0, b0);
        store_tile(acc[1], 1, b0);
    }

    half8 pf0h, pf0l, pf1h, pf1l;
    if (FASTW) {   // prefetch layer-2 ks=0 A (no LDS dependence) across barrier
        pf0h = *(const half8*)(pA00h - 2048);
        pf0l = *(const half8*)(pA00l - 2048);
        pf1h = *(const half8*)(pA01h - 2048);
        pf1l = *(const half8*)(pA01l - 2048);
    }
    __syncthreads();   // H1 visible

    // ---- Layer 2: H1 -> H2 (in place, barriered)
    gemm(0, pA00h, pA00l, pA01h, pA01l, pf0h, pf0l, pf1h, pf1l);
    if (FASTW) {   // prefetch layer-3 ks=0 A
        pf0h = *(const half8*)(pA10h - 2048);
        pf0l = *(const half8*)(pA10l - 2048);
        pf1h = *(const half8*)(pA11h - 2048);
        pf1l = *(const half8*)(pA11l - 2048);
    }
    __syncthreads();   // all waves done reading H1
    store_tile(acc[0], 0, b1);
    store_tile(acc[1], 1, b1);
    __syncthreads();   // H2 visible

    // ---- Layer 3 (+ Layer 4 reduce, no write-back)
    gemm(1, pA10h, pA10l, pA11h, pA11l, pf0h, pf0l, pf1h, pf1l);
    {
        float p = 0.f;
#pragma unroll
        for (int jt = 0; jt < 2; ++jt)
#pragma unroll
            for (int g = 0; g < 4; ++g) {
                int jg = jh * 64 + jt * 32 + 8 * g + 4 * lhi;
#pragma unroll
                for (int q = 0; q < 4; ++q) {
                    float v = fmaxf(acc[jt][g * 4 + q] + b2[jg + q], 0.f);
                    p = fmaf(v, w3[jg + q], p);
                }
            }
        p += __shfl_xor(p, 32);
        if (lane < 32) P2[jh * 128 + mrow] = p;
    }
    __syncthreads();
    if (tid < 128)
        sdf_out[base + tid] = b3[0] + P2[tid] + P2[128 + tid];
}

// One wave per ray: shfl scans for cdf, shfl binary-search for sample_pdf
// (exact searchsorted-count semantics on strictly-increasing cdf), then a
// 256-item bitonic KEY-VALUE sort (key = float-bits(d)<<32 | idx). Outputs
// raw fine d's (for the MLP) and the sorted provenance permutation.
__global__ __launch_bounds__(256) void sample_kernel(
    const float* __restrict__ sdf_c, const float* __restrict__ u,
    float* __restrict__ d_fine, unsigned char* __restrict__ perm8) {
    const int lane = threadIdx.x & 63, wv = threadIdx.x >> 6;
    const int ray = blockIdx.x * 4 + wv;

    float sv = sdf_c[ray * NC + lane];
    float c = 1.0f / (1.0f + expf(-100.0f * sv));
    float cn = __shfl_down(c, 1);
    bool valid = lane < 63;
    float a = valid ? fmaxf((c - cn) / (c + 1e-10f), 0.f) : 0.f;
    float sh = valid ? (1.f - a + 1e-10f) : 1.f;
    float ps = sh;
#pragma unroll
    for (int off = 1; off < 64; off <<= 1) { float o = __shfl_up(ps, off); if (lane >= off) ps *= o; }
    float T = __shfl_up(ps, 1);
    if (lane == 0) T = 1.f;
    float w = valid ? (a * T + 1e-5f) : 0.f;
    float wsum = w;
#pragma unroll
    for (int off = 1; off < 64; off <<= 1) wsum += __shfl_xor(wsum, off);
    float pdf = w / wsum;
    float cs = pdf;
#pragma unroll
    for (int off = 1; off < 64; off <<= 1) { float o = __shfl_up(cs, off); if (lane >= off) cs += o; }
    float cdfv = __shfl_up(cs, 1);
    if (lane == 0) cdfv = 0.f;    // cdf[lane], strictly increasing, cdf[0]=0

    float df[2];
#pragma unroll
    for (int t = 0; t < 2; ++t) {
        float uu = u[ray * NF + t * 64 + lane];
        int lo = 0;
#pragma unroll
        for (int b = 32; b >= 1; b >>= 1) {
            float cm = __shfl(cdfv, lo + b);
            if (uu >= cm) lo += b;
        }
        int above = min(lo + 1, NC - 1);
        float cb = __shfl(cdfv, lo), ca = __shfl(cdfv, above);
        float bb = dcoarse_at(lo), ba = dcoarse_at(above);
        float denom = ca - cb;
        if (denom < 1e-5f) denom = 1.f;
        float tt = (uu - cb) / denom;
        df[t] = bb + tt * (ba - bb);
        d_fine[ray * 128 + t * 64 + lane] = df[t];
    }

    ull v[4];
    v[0] = ((ull)__float_as_uint(dcoarse_at(lane)) << 32) | (unsigned)lane;
    v[1] = ((ull)__float_as_uint(df[0]) << 32) | (unsigned)(64 + lane);
    v[2] = ((ull)__float_as_uint(df[1]) << 32) | (unsigned)(128 + lane);
    v[3] = ((ull)0x7F800000u << 32) | 255u;   // +inf pad
    for (int k = 2; k <= 256; k <<= 1) {
        for (int j = k >> 1; j > 0; j >>= 1) {
            if (j >= 64) {
                int tj = j >> 6;
#pragma unroll
                for (int t = 0; t < 4; ++t) {
                    if ((t & tj) == 0) {
                        int t2 = t ^ tj;
                        bool asc = (((t * 64) & k) == 0);
                        ull x = v[t], y = v[t2];
                        bool sw = asc ? (x > y) : (x < y);
                        if (sw) { v[t] = y; v[t2] = x; }
                    }
                }
            } else {
#pragma unroll
                for (int t = 0; t < 4; ++t) {
                    int i = t * 64 + lane;
                    ull other = __shfl_xor(v[t], j);
                    bool lower = (lane & j) == 0;
                    bool asc = ((i & k) == 0);
                    bool takeMin = (lower == asc);
                    ull mn = v[t] < other ? v[t] : other;
                    ull mx = v[t] < other ? other : v[t];
                    v[t] = takeMin ? mn : mx;
                }
            }
        }
    }
#pragma unroll
    for (int t = 0; t < 3; ++t)
        perm8[ray * NALL + t * 64 + lane] = (unsigned char)(v[t] & 0xFFu);
}

// One wave per ray: gather sdf via permutation (idx<64 -> coarse, else fine),
// then chunked (3/lane) product scan for T, occu sum, out = 1-occu.
__global__ __launch_bounds__(256) void finish_kernel(
    const float* __restrict__ sdf_c, const float* __restrict__ sdf_f,
    const unsigned char* __restrict__ perm8, float* __restrict__ out) {
    int lane = threadIdx.x & 63, wv = threadIdx.x >> 6;
    int ray = blockIdx.x * 4 + wv;
    const unsigned char* P = perm8 + (size_t)ray * NALL;
    float c[4];
#pragma unroll
    for (int t = 0; t < 4; ++t) {
        int i = lane * 3 + t;
        if (i < NALL) {
            int idx = P[i];
            float s = (idx < 64) ? sdf_c[ray * NC + idx] : sdf_f[ray * 128 + (idx - 64)];
            c[t] = 1.0f / (1.0f + expf(-100.0f * s));
        } else c[t] = 0.f;
    }
    float a[3], s[3];
#pragma unroll
    for (int t = 0; t < 3; ++t) {
        int i = lane * 3 + t;
        if (i < NALL - 1) {
            a[t] = fmaxf((c[t] - c[t + 1]) / (c[t] + 1e-10f), 0.f);
            s[t] = 1.f - a[t] + 1e-10f;
        } else { a[t] = 0.f; s[t] = 1.f; }
    }
    float chunk = s[0] * s[1] * s[2];
    float ps = chunk;
#pragma unroll
    for (int off = 1; off < 64; off <<= 1) {
        float o = __shfl_up(ps, off);
        if (lane >= off) ps *= o;
    }
    float T = __shfl_up(ps, 1);
    if (lane == 0) T = 1.f;
    float occ = a[0] * T;
    T *= s[0]; occ = fmaf(a[1], T, occ);
    T *= s[1]; occ = fmaf(a[2], T, occ);
#pragma unroll
    for (int off = 1; off < 64; off <<= 1) occ += __shfl_xor(occ, off);
    if (lane == 0) out[ray] = 1.f - occ;
}

extern "C" void kernel_launch(void* const* d_in, const int* in_sizes, int n_in,
                              void* d_out, int out_size, void* d_ws, size_t ws_size,
                              hipStream_t stream) {
    const float* pts = (const float*)d_in[0];
    const float* lights = (const float*)d_in[1];
    const float* u = (const float*)d_in[2];
    const float* w0 = (const float*)d_in[3];
    const float* b0 = (const float*)d_in[4];
    const float* w1 = (const float*)d_in[5];
    const float* b1 = (const float*)d_in[6];
    const float* w2 = (const float*)d_in[7];
    const float* b2 = (const float*)d_in[8];
    const float* w3 = (const float*)d_in[9];
    const float* b3 = (const float*)d_in[10];
    float* out = (float*)d_out;

    // ws layout:
    //   sdf_c  : NRAY*64  f32   coarse sdf — persists to finish
    //   sdf_f  : NRAY*128 f32   fine sdf
    //   d_fine : NRAY*128 f32   raw fine sample depths
    //   perm8  : NRAY*192 u8    sorted provenance permutation
    //   Wsp    : 4*16384  f16   split weights
    char* wsb = (char*)d_ws;
    float* sdf_c = (float*)wsb;
    float* sdf_f = (float*)(wsb + (size_t)NRAY * NC * 4);
    float* d_fine = (float*)(wsb + (size_t)NRAY * (NC + 128) * 4);
    unsigned char* perm8 = (unsigned char*)(wsb + (size_t)NRAY * (NC + 256) * 4);
    _Float16* Wsp = (_Float16*)(wsb + (size_t)NRAY * (NC + 256) * 4 + (size_t)NRAY * NALL);
    const size_t need = (size_t)NRAY * (NC + 256) * 4 + (size_t)NRAY * NALL
                      + (size_t)4 * 16384 * sizeof(_Float16);
    const bool fast = ws_size >= need;

    if (fast) {
        prep_kernel<<<dim3(64, 2), 256, 0, stream>>>(w1, w2, Wsp);
        mlp_kernel<0, 1><<<(NRAY * NC) / 128, 512, 0, stream>>>(
            pts, lights, nullptr, w0, b0, w1, b1, w2, b2, w3, b3, Wsp, sdf_c);
        sample_kernel<<<NRAY / 4, 256, 0, stream>>>(sdf_c, u, d_fine, perm8);
        mlp_kernel<1, 1><<<(NRAY * 128) / 128, 512, 0, stream>>>(
            pts, lights, d_fine, w0, b0, w1, b1, w2, b2, w3, b3, Wsp, sdf_f);
    } else {
        mlp_kernel<0, 0><<<(NRAY * NC) / 128, 512, 0, stream>>>(
            pts, lights, nullptr, w0, b0, w1, b1, w2, b2, w3, b3, nullptr, sdf_c);
        sample_kernel<<<NRAY / 4, 256, 0, stream>>>(sdf_c, u, d_fine, perm8);
        mlp_kernel<1, 0><<<(NRAY * 128) / 128, 512, 0, stream>>>(
            pts, lights, d_fine, w0, b0, w1, b1, w2, b2, w3, b3, nullptr, sdf_f);
    }
    finish_kernel<<<NRAY / 4, 256, 0, stream>>>(sdf_c, sdf_f, perm8, out);
}

// Round 4
// 246.126 us; speedup vs baseline: 1.0926x; 1.0926x over previous
//
#include <hip/hip_runtime.h>
#include <math.h>

#define NL 8
#define NP 512
#define NC 64
#define NF 128
#define NALL 192
#define NRAY (NL * NP)
#define HID 128

typedef _Float16 half8 __attribute__((ext_vector_type(8)));
typedef _Float16 half4v __attribute__((ext_vector_type(4)));
typedef float floatx16 __attribute__((ext_vector_type(16)));
typedef unsigned long long ull;

#define MFMA(a, b, c) __builtin_amdgcn_mfma_f32_32x32x16_f16((a), (b), (c), 0, 0, 0)

// r18 = r16 (the 241us structure: 128-pt block, 8 waves jq*mh, A-dup 2x /
// B-dup 4x) + r17's addressing-only tricks:
//   - 16 hoisted swizzled LDS read addresses (computed once, reused by both
//     gemms — they read the same buffer)
//   - H planes merged: lo plane = +32768 byte immediate on the same ds_read
//     address register
//   - A pointers biased +4KB so all 8 ks offsets are signed-13-bit global
//     immediates off one base (kills per-ks 64-bit addr arithmetic)
// r17 post-mortem: the jh*mq remap REGRESSED (L2 A-traffic doubled; stall
// signature = both MfmaUtil and VALUBusy fell). LDS was not the limiter.
// Numerics: MFMA sequence + reduce association byte-identical to r16.

__device__ __forceinline__ float dcoarse_at(int i) {
    float t = (float)i * 0.015625f; // i/64, exact in fp32
    return 1e-3f * (1.0f - t) + 0.5f * t;
}

__device__ __forceinline__ floatx16 fzero16() {
    floatx16 z;
#pragma unroll
    for (int i = 0; i < 16; ++i) z[i] = 0.f;
    return z;
}
__device__ __forceinline__ half8 hzero8() {
    half8 z;
#pragma unroll
    for (int i = 0; i < 8; ++i) z[i] = (_Float16)0.f;
    return z;
}

// Wsp layout (per layer L in {0:w1, 1:w2}, plane p in {hi,lo}):
//   Wsp[(L*2+p)*16384 + f],  f = (((jb*8+ks)*2+lhi)*32 + l31)*8 + i
//   holding split(w[(ks*16+lhi*8+i)*128 + (jb*32+l31)]).
__global__ void prep_kernel(const float* __restrict__ w1, const float* __restrict__ w2,
                            _Float16* __restrict__ Wsp) {
    int f = blockIdx.x * 256 + threadIdx.x;   // [0, 16384)
    int layer = blockIdx.y;
    const float* w = layer ? w2 : w1;
    int i = f & 7, l31 = (f >> 3) & 31, lhi = (f >> 8) & 1, ks = (f >> 9) & 7, jb = f >> 12;
    int j = jb * 32 + l31;
    int k = ks * 16 + lhi * 8 + i;
    float v = w[k * 128 + j];
    _Float16 hi = (_Float16)v;
    Wsp[(layer * 2 + 0) * 16384 + f] = hi;
    Wsp[(layer * 2 + 1) * 16384 + f] = (_Float16)(v - (float)hi);
}

// Fused 4-layer MLP over 128 points per block, 8 waves, split-fp16 MFMA.
// MODE 0: coarse points (ray = pt>>6). MODE 1: fine points only (ray = pt>>7).
template<int MODE, int FASTW>
__global__ __launch_bounds__(512, 4) void mlp_kernel(
    const float* __restrict__ pts, const float* __restrict__ lights,
    const float* __restrict__ d_fine,
    const float* __restrict__ w0, const float* __restrict__ b0,
    const float* __restrict__ w1, const float* __restrict__ b1,
    const float* __restrict__ w2, const float* __restrict__ b2,
    const float* __restrict__ w3, const float* __restrict__ b3,
    const _Float16* __restrict__ Wsp,
    float* __restrict__ sdf_out)
{
    // H: hi plane at +0, lo plane at +32768 bytes (one address reg, two imms)
    __shared__ __align__(16) _Float16 H[2 * 128 * 128];
    __shared__ _Float16 Xs[6 * 128];   // hi c0,c1,c2 then lo c0,c1,c2
    __shared__ float P2[4 * 128];      // [jq][m]

    const int tid = threadIdx.x;
    const int lane = tid & 63;
    const int wv = tid >> 6;                 // 0..7
    const int jq = wv & 3, mh = wv >> 2;     // j quarter (32 cols), m half (64 rows)
    const int l31 = lane & 31, lhi = lane >> 5;
    const int base = blockIdx.x * 128;

    // ---- phase A: per-point coords, split to fp16 hi/lo in LDS
    if (tid < 128) {
        int pt = base + tid;
        int ray; float d;
        if (MODE == 0) { ray = pt >> 6; d = dcoarse_at(pt & 63); }
        else           { ray = pt >> 7; d = d_fine[pt]; }
        int l = ray >> 9, p = ray & (NP - 1);
        float px = pts[p * 3 + 0], py = pts[p * 3 + 1], pz = pts[p * 3 + 2];
        float dx = lights[l * 3 + 0] - px, dy = lights[l * 3 + 1] - py, dz = lights[l * 3 + 2] - pz;
        float n = sqrtf(dx * dx + dy * dy + dz * dz);
        dx /= n; dy /= n; dz /= n;
        float xc[3] = { px + d * dx, py + d * dy, pz + d * dz };
#pragma unroll
        for (int c = 0; c < 3; ++c) {
            _Float16 h = (_Float16)xc[c];
            Xs[c * 128 + tid] = h;
            Xs[(3 + c) * 128 + tid] = (_Float16)(xc[c] - (float)h);
        }
    }

    const int m0 = mh * 64;              // this wave's 64-pt half
    char* Hb = (char*)H;

    // Hoisted swizzled LDS read byte-offsets, identical for both gemms.
    // mrow(mt) = m0 + mt*32 + l31; k0 = ks*16 + lhi*8.
    int rdoff[2][8];
#pragma unroll
    for (int mt = 0; mt < 2; ++mt) {
        int mrow = m0 + mt * 32 + l31;
#pragma unroll
        for (int ks = 0; ks < 8; ++ks) {
            int k0 = ks * 16 + lhi * 8;
            rdoff[mt][ks] = (mrow * 128 + ((((k0 >> 3) ^ (mrow & 15)) << 3) | (k0 & 7))) * 2;
        }
    }

    auto store_tile = [&](const floatx16& a, int mt, const float* __restrict__ bias) {
        int mrow = m0 + mt * 32 + l31;
#pragma unroll
        for (int g = 0; g < 4; ++g) {
            int jg = jq * 32 + 8 * g + 4 * lhi;
            half4v hq, lq;
#pragma unroll
            for (int q = 0; q < 4; ++q) {
                float v = fmaxf(a[g * 4 + q] + bias[jg + q], 0.f);
                _Float16 hi = (_Float16)v;
                hq[q] = hi;
                lq[q] = (_Float16)(v - (float)hi);
            }
            int ad = (mrow * 128 + ((((jg >> 3) ^ (mrow & 15)) << 3) | (jg & 7))) * 2;
            *(half4v*)(Hb + ad) = hq;
            *(half4v*)(Hb + ad + 32768) = lq;
        }
    };

    floatx16 acc[2];   // [mt] — 32j x 64m per wave

    // A base pointers per (L, plane), biased +2048 halves so the 8 ks offsets
    // (ks*1024 - 4096 bytes) all fit the signed-13-bit global imm field.
    const int aoff = jq * 4096 + lhi * 256 + l31 * 8 + 2048;
    const _Float16* pA0h = Wsp + 0 * 16384 + aoff;
    const _Float16* pA0l = Wsp + 1 * 16384 + aoff;
    const _Float16* pA1h = Wsp + 2 * 16384 + aoff;
    const _Float16* pA1l = Wsp + 3 * 16384 + aoff;

    // Slow-path A fetch (fp32 weights, split on the fly) — correctness fallback.
    auto ldA_slow = [&](int L, int ks, half8& ah, half8& al) {
        const float* w = L ? w2 : w1;
        int j = jq * 32 + l31, k0 = ks * 16 + lhi * 8;
#pragma unroll
        for (int i = 0; i < 8; ++i) {
            float v = w[(k0 + i) * 128 + j];
            _Float16 hi = (_Float16)v;
            ah[i] = hi;
            al[i] = (_Float16)(v - (float)hi);
        }
    };

    // gemm over K=128: per ks, 2 global A loads (imm offsets) + 4 LDS B reads
    // (2 addr regs x 2 imms) + 6 MFMAs. pf* = prefetched ks=0 A fragments.
    auto gemm = [&](int L, const _Float16* ph, const _Float16* pl,
                    half8 pfh, half8 pfl) {
        acc[0] = fzero16(); acc[1] = fzero16();
#pragma unroll
        for (int ks = 0; ks < 8; ++ks) {
            half8 ah, al;
            if (FASTW) {
                if (ks == 0) { ah = pfh; al = pfl; }
                else {
                    ah = *(const half8*)(ph + ks * 512 - 2048);
                    al = *(const half8*)(pl + ks * 512 - 2048);
                }
            } else {
                ldA_slow(L, ks, ah, al);
            }
            half8 bh0 = *(const half8*)(Hb + rdoff[0][ks]);
            half8 bl0 = *(const half8*)(Hb + rdoff[0][ks] + 32768);
            half8 bh1 = *(const half8*)(Hb + rdoff[1][ks]);
            half8 bl1 = *(const half8*)(Hb + rdoff[1][ks] + 32768);
            acc[0] = MFMA(al, bh0, acc[0]); acc[1] = MFMA(al, bh1, acc[1]);
            acc[0] = MFMA(ah, bl0, acc[0]); acc[1] = MFMA(ah, bl1, acc[1]);
            acc[0] = MFMA(ah, bh0, acc[0]); acc[1] = MFMA(ah, bh1, acc[1]);
        }
    };

    __syncthreads();   // Xs visible

    // ---- Layer 1: 3->128 as one K=16 MFMA step (k>=3 zero-padded)
    {
        half8 a1h = hzero8(), a1l = hzero8(), bh1[2], bl1[2];
        bh1[0] = hzero8(); bh1[1] = hzero8(); bl1[0] = hzero8(); bl1[1] = hzero8();
        if (lhi == 0) {
            int j = jq * 32 + l31;
#pragma unroll
            for (int c = 0; c < 3; ++c) {
                float v = w0[c * 128 + j];
                _Float16 hi = (_Float16)v;
                a1h[c] = hi;
                a1l[c] = (_Float16)(v - (float)hi);
            }
#pragma unroll
            for (int mt = 0; mt < 2; ++mt) {
                int m = m0 + mt * 32 + l31;
#pragma unroll
                for (int c = 0; c < 3; ++c) {
                    bh1[mt][c] = Xs[c * 128 + m];
                    bl1[mt][c] = Xs[(3 + c) * 128 + m];
                }
            }
        }
        acc[0] = fzero16(); acc[1] = fzero16();
        acc[0] = MFMA(a1l, bh1[0], acc[0]); acc[1] = MFMA(a1l, bh1[1], acc[1]);
        acc[0] = MFMA(a1h, bl1[0], acc[0]); acc[1] = MFMA(a1h, bl1[1], acc[1]);
        acc[0] = MFMA(a1h, bh1[0], acc[0]); acc[1] = MFMA(a1h, bh1[1], acc[1]);
        store_tile(acc[0], 0, b0);
        store_tile(acc[1], 1, b0);
    }

    half8 pfh = hzero8(), pfl = hzero8();
    if (FASTW) {   // prefetch layer-2 ks=0 A (no LDS dependence) across barrier
        pfh = *(const half8*)(pA0h - 2048);
        pfl = *(const half8*)(pA0l - 2048);
    }
    __syncthreads();   // H1 visible

    // ---- Layer 2: H1 -> H2 (in place, barriered)
    gemm(0, pA0h, pA0l, pfh, pfl);
    if (FASTW) {   // prefetch layer-3 ks=0 A
        pfh = *(const half8*)(pA1h - 2048);
        pfl = *(const half8*)(pA1l - 2048);
    }
    __syncthreads();   // all waves done reading H1
    store_tile(acc[0], 0, b1);
    store_tile(acc[1], 1, b1);
    __syncthreads();   // H2 visible

    // ---- Layer 3 (+ Layer 4 reduce, no write-back)
    gemm(1, pA1h, pA1l, pfh, pfl);
#pragma unroll
    for (int mt = 0; mt < 2; ++mt) {
        float p = 0.f;
#pragma unroll
        for (int g = 0; g < 4; ++g) {
            int jg = jq * 32 + 8 * g + 4 * lhi;
#pragma unroll
            for (int q = 0; q < 4; ++q) {
                float v = fmaxf(acc[mt][g * 4 + q] + b2[jg + q], 0.f);
                p = fmaf(v, w3[jg + q], p);
            }
        }
        p += __shfl_xor(p, 32);
        if (lane < 32) P2[jq * 128 + m0 + mt * 32 + l31] = p;
    }
    __syncthreads();
    if (tid < 128)
        sdf_out[base + tid] = b3[0] + P2[tid] + P2[128 + tid] + P2[256 + tid] + P2[384 + tid];
}

// One wave per ray: shfl scans for cdf, shfl binary-search for sample_pdf
// (exact searchsorted-count semantics on strictly-increasing cdf), then a
// 256-item bitonic KEY-VALUE sort (key = float-bits(d)<<32 | idx). Outputs
// raw fine d's (for the MLP) and the sorted provenance permutation.
__global__ __launch_bounds__(256) void sample_kernel(
    const float* __restrict__ sdf_c, const float* __restrict__ u,
    float* __restrict__ d_fine, unsigned char* __restrict__ perm8) {
    const int lane = threadIdx.x & 63, wv = threadIdx.x >> 6;
    const int ray = blockIdx.x * 4 + wv;

    float sv = sdf_c[ray * NC + lane];
    float c = 1.0f / (1.0f + expf(-100.0f * sv));
    float cn = __shfl_down(c, 1);
    bool valid = lane < 63;
    float a = valid ? fmaxf((c - cn) / (c + 1e-10f), 0.f) : 0.f;
    float sh = valid ? (1.f - a + 1e-10f) : 1.f;
    float ps = sh;
#pragma unroll
    for (int off = 1; off < 64; off <<= 1) { float o = __shfl_up(ps, off); if (lane >= off) ps *= o; }
    float T = __shfl_up(ps, 1);
    if (lane == 0) T = 1.f;
    float w = valid ? (a * T + 1e-5f) : 0.f;
    float wsum = w;
#pragma unroll
    for (int off = 1; off < 64; off <<= 1) wsum += __shfl_xor(wsum, off);
    float pdf = w / wsum;
    float cs = pdf;
#pragma unroll
    for (int off = 1; off < 64; off <<= 1) { float o = __shfl_up(cs, off); if (lane >= off) cs += o; }
    float cdfv = __shfl_up(cs, 1);
    if (lane == 0) cdfv = 0.f;    // cdf[lane], strictly increasing, cdf[0]=0

    float df[2];
#pragma unroll
    for (int t = 0; t < 2; ++t) {
        float uu = u[ray * NF + t * 64 + lane];
        int lo = 0;
#pragma unroll
        for (int b = 32; b >= 1; b >>= 1) {
            float cm = __shfl(cdfv, lo + b);
            if (uu >= cm) lo += b;
        }
        int above = min(lo + 1, NC - 1);
        float cb = __shfl(cdfv, lo), ca = __shfl(cdfv, above);
        float bb = dcoarse_at(lo), ba = dcoarse_at(above);
        float denom = ca - cb;
        if (denom < 1e-5f) denom = 1.f;
        float tt = (uu - cb) / denom;
        df[t] = bb + tt * (ba - bb);
        d_fine[ray * 128 + t * 64 + lane] = df[t];
    }

    ull v[4];
    v[0] = ((ull)__float_as_uint(dcoarse_at(lane)) << 32) | (unsigned)lane;
    v[1] = ((ull)__float_as_uint(df[0]) << 32) | (unsigned)(64 + lane);
    v[2] = ((ull)__float_as_uint(df[1]) << 32) | (unsigned)(128 + lane);
    v[3] = ((ull)0x7F800000u << 32) | 255u;   // +inf pad
    for (int k = 2; k <= 256; k <<= 1) {
        for (int j = k >> 1; j > 0; j >>= 1) {
            if (j >= 64) {
                int tj = j >> 6;
#pragma unroll
                for (int t = 0; t < 4; ++t) {
                    if ((t & tj) == 0) {
                        int t2 = t ^ tj;
                        bool asc = (((t * 64) & k) == 0);
                        ull x = v[t], y = v[t2];
                        bool sw = asc ? (x > y) : (x < y);
                        if (sw) { v[t] = y; v[t2] = x; }
                    }
                }
            } else {
#pragma unroll
                for (int t = 0; t < 4; ++t) {
                    int i = t * 64 + lane;
                    ull other = __shfl_xor(v[t], j);
                    bool lower = (lane & j) == 0;
                    bool asc = ((i & k) == 0);
                    bool takeMin = (lower == asc);
                    ull mn = v[t] < other ? v[t] : other;
                    ull mx = v[t] < other ? other : v[t];
                    v[t] = takeMin ? mn : mx;
                }
            }
        }
    }
#pragma unroll
    for (int t = 0; t < 3; ++t)
        perm8[ray * NALL + t * 64 + lane] = (unsigned char)(v[t] & 0xFFu);
}

// One wave per ray: gather sdf via permutation (idx<64 -> coarse, else fine),
// then chunked (3/lane) product scan for T, occu sum, out = 1-occu.
__global__ __launch_bounds__(256) void finish_kernel(
    const float* __restrict__ sdf_c, const float* __restrict__ sdf_f,
    const unsigned char* __restrict__ perm8, float* __restrict__ out) {
    int lane = threadIdx.x & 63, wv = threadIdx.x >> 6;
    int ray = blockIdx.x * 4 + wv;
    const unsigned char* P = perm8 + (size_t)ray * NALL;
    float c[4];
#pragma unroll
    for (int t = 0; t < 4; ++t) {
        int i = lane * 3 + t;
        if (i < NALL) {
            int idx = P[i];
            float s = (idx < 64) ? sdf_c[ray * NC + idx] : sdf_f[ray * 128 + (idx - 64)];
            c[t] = 1.0f / (1.0f + expf(-100.0f * s));
        } else c[t] = 0.f;
    }
    float a[3], s[3];
#pragma unroll
    for (int t = 0; t < 3; ++t) {
        int i = lane * 3 + t;
        if (i < NALL - 1) {
            a[t] = fmaxf((c[t] - c[t + 1]) / (c[t] + 1e-10f), 0.f);
            s[t] = 1.f - a[t] + 1e-10f;
        } else { a[t] = 0.f; s[t] = 1.f; }
    }
    float chunk = s[0] * s[1] * s[2];
    float ps = chunk;
#pragma unroll
    for (int off = 1; off < 64; off <<= 1) {
        float o = __shfl_up(ps, off);
        if (lane >= off) ps *= o;
    }
    float T = __shfl_up(ps, 1);
    if (lane == 0) T = 1.f;
    float occ = a[0] * T;
    T *= s[0]; occ = fmaf(a[1], T, occ);
    T *= s[1]; occ = fmaf(a[2], T, occ);
#pragma unroll
    for (int off = 1; off < 64; off <<= 1) occ += __shfl_xor(occ, off);
    if (lane == 0) out[ray] = 1.f - occ;
}

extern "C" void kernel_launch(void* const* d_in, const int* in_sizes, int n_in,
                              void* d_out, int out_size, void* d_ws, size_t ws_size,
                              hipStream_t stream) {
    const float* pts = (const float*)d_in[0];
    const float* lights = (const float*)d_in[1];
    const float* u = (const float*)d_in[2];
    const float* w0 = (const float*)d_in[3];
    const float* b0 = (const float*)d_in[4];
    const float* w1 = (const float*)d_in[5];
    const float* b1 = (const float*)d_in[6];
    const float* w2 = (const float*)d_in[7];
    const float* b2 = (const float*)d_in[8];
    const float* w3 = (const float*)d_in[9];
    const float* b3 = (const float*)d_in[10];
    float* out = (float*)d_out;

    // ws layout:
    //   sdf_c  : NRAY*64  f32   coarse sdf — persists to finish
    //   sdf_f  : NRAY*128 f32   fine sdf
    //   d_fine : NRAY*128 f32   raw fine sample depths
    //   perm8  : NRAY*192 u8    sorted provenance permutation
    //   Wsp    : 4*16384  f16   split weights
    char* wsb = (char*)d_ws;
    float* sdf_c = (float*)wsb;
    float* sdf_f = (float*)(wsb + (size_t)NRAY * NC * 4);
    float* d_fine = (float*)(wsb + (size_t)NRAY * (NC + 128) * 4);
    unsigned char* perm8 = (unsigned char*)(wsb + (size_t)NRAY * (NC + 256) * 4);
    _Float16* Wsp = (_Float16*)(wsb + (size_t)NRAY * (NC + 256) * 4 + (size_t)NRAY * NALL);
    const size_t need = (size_t)NRAY * (NC + 256) * 4 + (size_t)NRAY * NALL
                      + (size_t)4 * 16384 * sizeof(_Float16);
    const bool fast = ws_size >= need;

    if (fast) {
        prep_kernel<<<dim3(64, 2), 256, 0, stream>>>(w1, w2, Wsp);
        mlp_kernel<0, 1><<<(NRAY * NC) / 128, 512, 0, stream>>>(
            pts, lights, nullptr, w0, b0, w1, b1, w2, b2, w3, b3, Wsp, sdf_c);
        sample_kernel<<<NRAY / 4, 256, 0, stream>>>(sdf_c, u, d_fine, perm8);
        mlp_kernel<1, 1><<<(NRAY * 128) / 128, 512, 0, stream>>>(
            pts, lights, d_fine, w0, b0, w1, b1, w2, b2, w3, b3, Wsp, sdf_f);
    } else {
        mlp_kernel<0, 0><<<(NRAY * NC) / 128, 512, 0, stream>>>(
            pts, lights, nullptr, w0, b0, w1, b1, w2, b2, w3, b3, nullptr, sdf_c);
        sample_kernel<<<NRAY / 4, 256, 0, stream>>>(sdf_c, u, d_fine, perm8);
        mlp_kernel<1, 0><<<(NRAY * 128) / 128, 512, 0, stream>>>(
            pts, lights, d_fine, w0, b0, w1, b1, w2, b2, w3, b3, nullptr, sdf_f);
    }
    finish_kernel<<<NRAY / 4, 256, 0, stream>>>(sdf_c, sdf_f, perm8, out);
}

// Round 5
// 241.653 us; speedup vs baseline: 1.1128x; 1.0185x over previous
//
#include <hip/hip_runtime.h>
#include <math.h>

#define NL 8
#define NP 512
#define NC 64
#define NF 128
#define NALL 192
#define NRAY (NL * NP)
#define HID 128

typedef _Float16 half8 __attribute__((ext_vector_type(8)));
typedef _Float16 half4v __attribute__((ext_vector_type(4)));
typedef float floatx16 __attribute__((ext_vector_type(16)));
typedef unsigned long long ull;

#define MFMA(a, b, c) __builtin_amdgcn_mfma_f32_32x32x16_f16((a), (b), (c), 0, 0, 0)

// r19 = r18 structure (128-pt block, 8 waves jq*mh, hoisted LDS addrs) +
// register-pipelined A-stream across barriers:
//   - A[ks0..3] for each gemm preloaded BEFORE the barrier that opens it
//     (L2 latency covered by the preceding compute phase, not paid inside
//     the barrier-bounded gemm)
//   - in-loop: iteration ks issues the load for ks+4 (depth-4 pipeline);
//     no MFMA waits on a load issued < 4 ks earlier
//   - rdoff compacted 16 -> 8 VGPRs: (mrow+32)&15 == mrow&15, so the mt=1
//     B-read is a +8192 DS immediate on the mt=0 address register
//     (planes: hi+0 / hi+8192 / lo+32768 / lo+40960, one addr reg per ks)
// r18 post-mortem: VALU-cut was neutral -> stall fraction (~20%, cold A-load
// queue at each phase start) is the target, not instruction count.
// Numerics: MFMA sequence + reduce association byte-identical to r18.

__device__ __forceinline__ float dcoarse_at(int i) {
    float t = (float)i * 0.015625f; // i/64, exact in fp32
    return 1e-3f * (1.0f - t) + 0.5f * t;
}

__device__ __forceinline__ floatx16 fzero16() {
    floatx16 z;
#pragma unroll
    for (int i = 0; i < 16; ++i) z[i] = 0.f;
    return z;
}
__device__ __forceinline__ half8 hzero8() {
    half8 z;
#pragma unroll
    for (int i = 0; i < 8; ++i) z[i] = (_Float16)0.f;
    return z;
}

// Wsp layout (per layer L in {0:w1, 1:w2}, plane p in {hi,lo}):
//   Wsp[(L*2+p)*16384 + f],  f = (((jb*8+ks)*2+lhi)*32 + l31)*8 + i
//   holding split(w[(ks*16+lhi*8+i)*128 + (jb*32+l31)]).
__global__ void prep_kernel(const float* __restrict__ w1, const float* __restrict__ w2,
                            _Float16* __restrict__ Wsp) {
    int f = blockIdx.x * 256 + threadIdx.x;   // [0, 16384)
    int layer = blockIdx.y;
    const float* w = layer ? w2 : w1;
    int i = f & 7, l31 = (f >> 3) & 31, lhi = (f >> 8) & 1, ks = (f >> 9) & 7, jb = f >> 12;
    int j = jb * 32 + l31;
    int k = ks * 16 + lhi * 8 + i;
    float v = w[k * 128 + j];
    _Float16 hi = (_Float16)v;
    Wsp[(layer * 2 + 0) * 16384 + f] = hi;
    Wsp[(layer * 2 + 1) * 16384 + f] = (_Float16)(v - (float)hi);
}

// Fused 4-layer MLP over 128 points per block, 8 waves, split-fp16 MFMA.
// MODE 0: coarse points (ray = pt>>6). MODE 1: fine points only (ray = pt>>7).
template<int MODE, int FASTW>
__global__ __launch_bounds__(512, 4) void mlp_kernel(
    const float* __restrict__ pts, const float* __restrict__ lights,
    const float* __restrict__ d_fine,
    const float* __restrict__ w0, const float* __restrict__ b0,
    const float* __restrict__ w1, const float* __restrict__ b1,
    const float* __restrict__ w2, const float* __restrict__ b2,
    const float* __restrict__ w3, const float* __restrict__ b3,
    const _Float16* __restrict__ Wsp,
    float* __restrict__ sdf_out)
{
    // H: hi plane at +0, lo plane at +32768 bytes (one address reg, imms)
    __shared__ __align__(16) _Float16 H[2 * 128 * 128];
    __shared__ _Float16 Xs[6 * 128];   // hi c0,c1,c2 then lo c0,c1,c2
    __shared__ float P2[4 * 128];      // [jq][m]

    const int tid = threadIdx.x;
    const int lane = tid & 63;
    const int wv = tid >> 6;                 // 0..7
    const int jq = wv & 3, mh = wv >> 2;     // j quarter (32 cols), m half (64 rows)
    const int l31 = lane & 31, lhi = lane >> 5;
    const int base = blockIdx.x * 128;

    // ---- phase A: per-point coords, split to fp16 hi/lo in LDS
    if (tid < 128) {
        int pt = base + tid;
        int ray; float d;
        if (MODE == 0) { ray = pt >> 6; d = dcoarse_at(pt & 63); }
        else           { ray = pt >> 7; d = d_fine[pt]; }
        int l = ray >> 9, p = ray & (NP - 1);
        float px = pts[p * 3 + 0], py = pts[p * 3 + 1], pz = pts[p * 3 + 2];
        float dx = lights[l * 3 + 0] - px, dy = lights[l * 3 + 1] - py, dz = lights[l * 3 + 2] - pz;
        float n = sqrtf(dx * dx + dy * dy + dz * dz);
        dx /= n; dy /= n; dz /= n;
        float xc[3] = { px + d * dx, py + d * dy, pz + d * dz };
#pragma unroll
        for (int c = 0; c < 3; ++c) {
            _Float16 h = (_Float16)xc[c];
            Xs[c * 128 + tid] = h;
            Xs[(3 + c) * 128 + tid] = (_Float16)(xc[c] - (float)h);
        }
    }

    const int m0 = mh * 64;              // this wave's 64-pt half
    const int mrow0 = m0 + l31;          // mt=0 LDS row (mt=1 = +32 rows = +8192 B)
    char* Hb = (char*)H;

    // Hoisted swizzled LDS read byte-offsets for mt=0 (mt=1 via +8192 imm;
    // valid because (mrow0+32)&15 == mrow0&15). Identical for both gemms.
    int rdoff[8];
#pragma unroll
    for (int ks = 0; ks < 8; ++ks) {
        int k0 = ks * 16 + lhi * 8;
        rdoff[ks] = (mrow0 * 128 + ((((k0 >> 3) ^ (mrow0 & 15)) << 3) | (k0 & 7))) * 2;
    }

    auto store_tile = [&](const floatx16& a, int mt, const float* __restrict__ bias) {
        int mrow = mrow0 + mt * 32;
#pragma unroll
        for (int g = 0; g < 4; ++g) {
            int jg = jq * 32 + 8 * g + 4 * lhi;
            half4v hq, lq;
#pragma unroll
            for (int q = 0; q < 4; ++q) {
                float v = fmaxf(a[g * 4 + q] + bias[jg + q], 0.f);
                _Float16 hi = (_Float16)v;
                hq[q] = hi;
                lq[q] = (_Float16)(v - (float)hi);
            }
            int ad = (mrow * 128 + ((((jg >> 3) ^ (mrow & 15)) << 3) | (jg & 7))) * 2;
            *(half4v*)(Hb + ad) = hq;
            *(half4v*)(Hb + ad + 32768) = lq;
        }
    };

    floatx16 acc[2];   // [mt] — 32j x 64m per wave

    // A base pointers per (L, plane), biased +2048 halves so the 8 ks offsets
    // (ks*1024 - 4096 bytes) all fit the signed-13-bit global imm field.
    const int aoff = jq * 4096 + lhi * 256 + l31 * 8 + 2048;
    const _Float16* pA0h = Wsp + 0 * 16384 + aoff;
    const _Float16* pA0l = Wsp + 1 * 16384 + aoff;
    const _Float16* pA1h = Wsp + 2 * 16384 + aoff;
    const _Float16* pA1l = Wsp + 3 * 16384 + aoff;

    // Slow-path A fetch (fp32 weights, split on the fly) — correctness fallback.
    auto ldA_slow = [&](int L, int ks, half8& ah, half8& al) {
        const float* w = L ? w2 : w1;
        int j = jq * 32 + l31, k0 = ks * 16 + lhi * 8;
#pragma unroll
        for (int i = 0; i < 8; ++i) {
            float v = w[(k0 + i) * 128 + j];
            _Float16 hi = (_Float16)v;
            ah[i] = hi;
            al[i] = (_Float16)(v - (float)hi);
        }
    };

    // Register-pipelined A stream (depth 4).
    half8 Ah[8], Al[8];
    auto preload4 = [&](int L, const _Float16* ph, const _Float16* pl) {
        if (FASTW) {
#pragma unroll
            for (int ks = 0; ks < 4; ++ks) {
                Ah[ks] = *(const half8*)(ph + ks * 512 - 2048);
                Al[ks] = *(const half8*)(pl + ks * 512 - 2048);
            }
        } else {
#pragma unroll
            for (int ks = 0; ks < 4; ++ks) ldA_slow(L, ks, Ah[ks], Al[ks]);
        }
    };

    // gemm over K=128: B via 1 addr reg + 3 DS imms per ks; A from the reg
    // pipeline, iteration ks issues the ks+4 load (never a cold queue).
    auto gemm = [&](int L, const _Float16* ph, const _Float16* pl) {
        acc[0] = fzero16(); acc[1] = fzero16();
#pragma unroll
        for (int ks = 0; ks < 8; ++ks) {
            if (ks < 4) {
                if (FASTW) {
                    Ah[ks + 4] = *(const half8*)(ph + (ks + 4) * 512 - 2048);
                    Al[ks + 4] = *(const half8*)(pl + (ks + 4) * 512 - 2048);
                } else {
                    ldA_slow(L, ks + 4, Ah[ks + 4], Al[ks + 4]);
                }
            }
            char* ba = Hb + rdoff[ks];
            half8 bh0 = *(const half8*)(ba);
            half8 bh1 = *(const half8*)(ba + 8192);
            half8 bl0 = *(const half8*)(ba + 32768);
            half8 bl1 = *(const half8*)(ba + 40960);
            acc[0] = MFMA(Al[ks], bh0, acc[0]); acc[1] = MFMA(Al[ks], bh1, acc[1]);
            acc[0] = MFMA(Ah[ks], bl0, acc[0]); acc[1] = MFMA(Ah[ks], bl1, acc[1]);
            acc[0] = MFMA(Ah[ks], bh0, acc[0]); acc[1] = MFMA(Ah[ks], bh1, acc[1]);
        }
    };

    __syncthreads();   // Xs visible

    // ---- Layer 1: 3->128 as one K=16 MFMA step (k>=3 zero-padded)
    {
        half8 a1h = hzero8(), a1l = hzero8(), bh1[2], bl1[2];
        bh1[0] = hzero8(); bh1[1] = hzero8(); bl1[0] = hzero8(); bl1[1] = hzero8();
        if (lhi == 0) {
            int j = jq * 32 + l31;
#pragma unroll
            for (int c = 0; c < 3; ++c) {
                float v = w0[c * 128 + j];
                _Float16 hi = (_Float16)v;
                a1h[c] = hi;
                a1l[c] = (_Float16)(v - (float)hi);
            }
#pragma unroll
            for (int mt = 0; mt < 2; ++mt) {
                int m = m0 + mt * 32 + l31;
#pragma unroll
                for (int c = 0; c < 3; ++c) {
                    bh1[mt][c] = Xs[c * 128 + m];
                    bl1[mt][c] = Xs[(3 + c) * 128 + m];
                }
            }
        }
        acc[0] = fzero16(); acc[1] = fzero16();
        acc[0] = MFMA(a1l, bh1[0], acc[0]); acc[1] = MFMA(a1l, bh1[1], acc[1]);
        acc[0] = MFMA(a1h, bl1[0], acc[0]); acc[1] = MFMA(a1h, bl1[1], acc[1]);
        acc[0] = MFMA(a1h, bh1[0], acc[0]); acc[1] = MFMA(a1h, bh1[1], acc[1]);
        store_tile(acc[0], 0, b0);
        store_tile(acc[1], 1, b0);
    }

    preload4(0, pA0h, pA0l);   // gemm0 A[0..3] in flight across the barrier
    __syncthreads();   // H1 visible

    // ---- Layer 2: H1 -> H2 (in place, barriered)
    gemm(0, pA0h, pA0l);
    preload4(1, pA1h, pA1l);   // gemm1 A[0..3] in flight across store+barriers
    __syncthreads();   // all waves done reading H1
    store_tile(acc[0], 0, b1);
    store_tile(acc[1], 1, b1);
    __syncthreads();   // H2 visible

    // ---- Layer 3 (+ Layer 4 reduce, no write-back)
    gemm(1, pA1h, pA1l);
#pragma unroll
    for (int mt = 0; mt < 2; ++mt) {
        float p = 0.f;
#pragma unroll
        for (int g = 0; g < 4; ++g) {
            int jg = jq * 32 + 8 * g + 4 * lhi;
#pragma unroll
            for (int q = 0; q < 4; ++q) {
                float v = fmaxf(acc[mt][g * 4 + q] + b2[jg + q], 0.f);
                p = fmaf(v, w3[jg + q], p);
            }
        }
        p += __shfl_xor(p, 32);
        if (lane < 32) P2[jq * 128 + m0 + mt * 32 + l31] = p;
    }
    __syncthreads();
    if (tid < 128)
        sdf_out[base + tid] = b3[0] + P2[tid] + P2[128 + tid] + P2[256 + tid] + P2[384 + tid];
}

// One wave per ray: shfl scans for cdf, shfl binary-search for sample_pdf
// (exact searchsorted-count semantics on strictly-increasing cdf), then a
// 256-item bitonic KEY-VALUE sort (key = float-bits(d)<<32 | idx). Outputs
// raw fine d's (for the MLP) and the sorted provenance permutation.
__global__ __launch_bounds__(256) void sample_kernel(
    const float* __restrict__ sdf_c, const float* __restrict__ u,
    float* __restrict__ d_fine, unsigned char* __restrict__ perm8) {
    const int lane = threadIdx.x & 63, wv = threadIdx.x >> 6;
    const int ray = blockIdx.x * 4 + wv;

    float sv = sdf_c[ray * NC + lane];
    float c = 1.0f / (1.0f + expf(-100.0f * sv));
    float cn = __shfl_down(c, 1);
    bool valid = lane < 63;
    float a = valid ? fmaxf((c - cn) / (c + 1e-10f), 0.f) : 0.f;
    float sh = valid ? (1.f - a + 1e-10f) : 1.f;
    float ps = sh;
#pragma unroll
    for (int off = 1; off < 64; off <<= 1) { float o = __shfl_up(ps, off); if (lane >= off) ps *= o; }
    float T = __shfl_up(ps, 1);
    if (lane == 0) T = 1.f;
    float w = valid ? (a * T + 1e-5f) : 0.f;
    float wsum = w;
#pragma unroll
    for (int off = 1; off < 64; off <<= 1) wsum += __shfl_xor(wsum, off);
    float pdf = w / wsum;
    float cs = pdf;
#pragma unroll
    for (int off = 1; off < 64; off <<= 1) { float o = __shfl_up(cs, off); if (lane >= off) cs += o; }
    float cdfv = __shfl_up(cs, 1);
    if (lane == 0) cdfv = 0.f;    // cdf[lane], strictly increasing, cdf[0]=0

    float df[2];
#pragma unroll
    for (int t = 0; t < 2; ++t) {
        float uu = u[ray * NF + t * 64 + lane];
        int lo = 0;
#pragma unroll
        for (int b = 32; b >= 1; b >>= 1) {
            float cm = __shfl(cdfv, lo + b);
            if (uu >= cm) lo += b;
        }
        int above = min(lo + 1, NC - 1);
        float cb = __shfl(cdfv, lo), ca = __shfl(cdfv, above);
        float bb = dcoarse_at(lo), ba = dcoarse_at(above);
        float denom = ca - cb;
        if (denom < 1e-5f) denom = 1.f;
        float tt = (uu - cb) / denom;
        df[t] = bb + tt * (ba - bb);
        d_fine[ray * 128 + t * 64 + lane] = df[t];
    }

    ull v[4];
    v[0] = ((ull)__float_as_uint(dcoarse_at(lane)) << 32) | (unsigned)lane;
    v[1] = ((ull)__float_as_uint(df[0]) << 32) | (unsigned)(64 + lane);
    v[2] = ((ull)__float_as_uint(df[1]) << 32) | (unsigned)(128 + lane);
    v[3] = ((ull)0x7F800000u << 32) | 255u;   // +inf pad
    for (int k = 2; k <= 256; k <<= 1) {
        for (int j = k >> 1; j > 0; j >>= 1) {
            if (j >= 64) {
                int tj = j >> 6;
#pragma unroll
                for (int t = 0; t < 4; ++t) {
                    if ((t & tj) == 0) {
                        int t2 = t ^ tj;
                        bool asc = (((t * 64) & k) == 0);
                        ull x = v[t], y = v[t2];
                        bool sw = asc ? (x > y) : (x < y);
                        if (sw) { v[t] = y; v[t2] = x; }
                    }
                }
            } else {
#pragma unroll
                for (int t = 0; t < 4; ++t) {
                    int i = t * 64 + lane;
                    ull other = __shfl_xor(v[t], j);
                    bool lower = (lane & j) == 0;
                    bool asc = ((i & k) == 0);
                    bool takeMin = (lower == asc);
                    ull mn = v[t] < other ? v[t] : other;
                    ull mx = v[t] < other ? other : v[t];
                    v[t] = takeMin ? mn : mx;
                }
            }
        }
    }
#pragma unroll
    for (int t = 0; t < 3; ++t)
        perm8[ray * NALL + t * 64 + lane] = (unsigned char)(v[t] & 0xFFu);
}

// One wave per ray: gather sdf via permutation (idx<64 -> coarse, else fine),
// then chunked (3/lane) product scan for T, occu sum, out = 1-occu.
__global__ __launch_bounds__(256) void finish_kernel(
    const float* __restrict__ sdf_c, const float* __restrict__ sdf_f,
    const unsigned char* __restrict__ perm8, float* __restrict__ out) {
    int lane = threadIdx.x & 63, wv = threadIdx.x >> 6;
    int ray = blockIdx.x * 4 + wv;
    const unsigned char* P = perm8 + (size_t)ray * NALL;
    float c[4];
#pragma unroll
    for (int t = 0; t < 4; ++t) {
        int i = lane * 3 + t;
        if (i < NALL) {
            int idx = P[i];
            float s = (idx < 64) ? sdf_c[ray * NC + idx] : sdf_f[ray * 128 + (idx - 64)];
            c[t] = 1.0f / (1.0f + expf(-100.0f * s));
        } else c[t] = 0.f;
    }
    float a[3], s[3];
#pragma unroll
    for (int t = 0; t < 3; ++t) {
        int i = lane * 3 + t;
        if (i < NALL - 1) {
            a[t] = fmaxf((c[t] - c[t + 1]) / (c[t] + 1e-10f), 0.f);
            s[t] = 1.f - a[t] + 1e-10f;
        } else { a[t] = 0.f; s[t] = 1.f; }
    }
    float chunk = s[0] * s[1] * s[2];
    float ps = chunk;
#pragma unroll
    for (int off = 1; off < 64; off <<= 1) {
        float o = __shfl_up(ps, off);
        if (lane >= off) ps *= o;
    }
    float T = __shfl_up(ps, 1);
    if (lane == 0) T = 1.f;
    float occ = a[0] * T;
    T *= s[0]; occ = fmaf(a[1], T, occ);
    T *= s[1]; occ = fmaf(a[2], T, occ);
#pragma unroll
    for (int off = 1; off < 64; off <<= 1) occ += __shfl_xor(occ, off);
    if (lane == 0) out[ray] = 1.f - occ;
}

extern "C" void kernel_launch(void* const* d_in, const int* in_sizes, int n_in,
                              void* d_out, int out_size, void* d_ws, size_t ws_size,
                              hipStream_t stream) {
    const float* pts = (const float*)d_in[0];
    const float* lights = (const float*)d_in[1];
    const float* u = (const float*)d_in[2];
    const float* w0 = (const float*)d_in[3];
    const float* b0 = (const float*)d_in[4];
    const float* w1 = (const float*)d_in[5];
    const float* b1 = (const float*)d_in[6];
    const float* w2 = (const float*)d_in[7];
    const float* b2 = (const float*)d_in[8];
    const float* w3 = (const float*)d_in[9];
    const float* b3 = (const float*)d_in[10];
    float* out = (float*)d_out;

    // ws layout:
    //   sdf_c  : NRAY*64  f32   coarse sdf — persists to finish
    //   sdf_f  : NRAY*128 f32   fine sdf
    //   d_fine : NRAY*128 f32   raw fine sample depths
    //   perm8  : NRAY*192 u8    sorted provenance permutation
    //   Wsp    : 4*16384  f16   split weights
    char* wsb = (char*)d_ws;
    float* sdf_c = (float*)wsb;
    float* sdf_f = (float*)(wsb + (size_t)NRAY * NC * 4);
    float* d_fine = (float*)(wsb + (size_t)NRAY * (NC + 128) * 4);
    unsigned char* perm8 = (unsigned char*)(wsb + (size_t)NRAY * (NC + 256) * 4);
    _Float16* Wsp = (_Float16*)(wsb + (size_t)NRAY * (NC + 256) * 4 + (size_t)NRAY * NALL);
    const size_t need = (size_t)NRAY * (NC + 256) * 4 + (size_t)NRAY * NALL
                      + (size_t)4 * 16384 * sizeof(_Float16);
    const bool fast = ws_size >= need;

    if (fast) {
        prep_kernel<<<dim3(64, 2), 256, 0, stream>>>(w1, w2, Wsp);
        mlp_kernel<0, 1><<<(NRAY * NC) / 128, 512, 0, stream>>>(
            pts, lights, nullptr, w0, b0, w1, b1, w2, b2, w3, b3, Wsp, sdf_c);
        sample_kernel<<<NRAY / 4, 256, 0, stream>>>(sdf_c, u, d_fine, perm8);
        mlp_kernel<1, 1><<<(NRAY * 128) / 128, 512, 0, stream>>>(
            pts, lights, d_fine, w0, b0, w1, b1, w2, b2, w3, b3, Wsp, sdf_f);
    } else {
        mlp_kernel<0, 0><<<(NRAY * NC) / 128, 512, 0, stream>>>(
            pts, lights, nullptr, w0, b0, w1, b1, w2, b2, w3, b3, nullptr, sdf_c);
        sample_kernel<<<NRAY / 4, 256, 0, stream>>>(sdf_c, u, d_fine, perm8);
        mlp_kernel<1, 0><<<(NRAY * 128) / 128, 512, 0, stream>>>(
            pts, lights, d_fine, w0, b0, w1, b1, w2, b2, w3, b3, nullptr, sdf_f);
    }
    finish_kernel<<<NRAY / 4, 256, 0, stream>>>(sdf_c, sdf_f, perm8, out);
}